// Round 7
// baseline (386.963 us; speedup 1.0000x reference)
//
#include <hip/hip_runtime.h>
#include <hip/hip_fp16.h>
#include <math.h>

// Problem constants (x: [32,64,64,64] f32, embedding: [64,1024] f32)
#define NPIX   131072
#define DDIM   64
#define KCODE  1024
#define BETA   0.25f
#define EPS2   4e-3f      // top-2 gap threshold triggering exact fp32 fix-up
#define FIXCAP 2048

// d_out layout (float32), in reference return order:
#define Q_OFF    0
#define LOSS_OFF 8388608
#define PERP_OFF 8388609
#define ENC_OFF  8388610   // NOTE: byte base ≡ 8 (mod 16) -> enc+2 is 16B-aligned
#define IDX_OFF  142606338

// scratch parked inside the enc region (float offsets from enc base); all of
// it is overwritten by vq_fill afterwards.
#define CAND_F     0          // float2[8][NPIX][2] candidate entries (16 MB)
#define EHT_F      4194306    // f16[1024][64] hi   (byte off ≡ 8 -> abs ≡ 0 mod 16)
#define ELT_F      4227078    // f16[1024][64] lo
#define FIXLIST_I  4259848    // int[FIXCAP]
#define FIXCOUNT_I 4261896    // int

// ws layout (bytes):
//   [0,32768) loss partials f32[8192]; [32768,36864) hist int[1024];
//   [36864,40960) norms f32[1024];     [40960,303104) embT f32[1024][64]

typedef _Float16 half8 __attribute__((ext_vector_type(8)));
typedef float    f32x4 __attribute__((ext_vector_type(4)));

// ---------- prep: transpose to embT, f16 hi/lo split ----------
__global__ void vq_prep(const float* __restrict__ emb, float* __restrict__ embT,
                        __half* __restrict__ eh, __half* __restrict__ el) {
    int i = blockIdx.x * 256 + threadIdx.x;   // over 65536
    int d = i >> 10;
    int k = i & 1023;
    float v = emb[i];
    embT[k * DDIM + d] = v;
    _Float16 h = (_Float16)v;
    _Float16 l = (_Float16)(v - (float)h);
    ((_Float16*)eh)[k * DDIM + d] = h;
    ((_Float16*)el)[k * DDIM + d] = l;
}

__global__ void vq_norms(const float* __restrict__ emb, float* __restrict__ norms) {
    int k = blockIdx.x * 256 + threadIdx.x;   // over 1024
    float s = 0.f;
    #pragma unroll 8
    for (int d = 0; d < DDIM; ++d) {
        float v = emb[d * KCODE + k];
        s = fmaf(v, v, s);
    }
    norms[k] = s;
}

// ---------- MFMA argmin: block = 4 waves x 32 pixels, 128-code panel ----------
// Grid (NPIX/128, 8): 8192 blocks -> block turnover hides panel staging.
// dist = ||e||^2 - 2 x.e. dot via 3 f16-split MFMAs. Per-pixel top-2 per split.
__global__ __launch_bounds__(256) void vq_argmin_mfma(
        const float* __restrict__ x, const __half* __restrict__ eh,
        const __half* __restrict__ el, const float* __restrict__ norms,
        float2* __restrict__ cand) {
    __shared__ char lds_raw[33280];
    half8* EH8 = (half8*)lds_raw;              // [128 codes][8 granules] swizzled
    half8* EL8 = (half8*)(lds_raw + 16384);
    float* NRM = (float*)(lds_raw + 32768);    // [128]

    const int tid   = threadIdx.x;
    const int kbase = blockIdx.y * 128;

    // stage e panel with XOR granule swizzle (granule g -> g ^ (code&7))
    {
        const float4* sh = (const float4*)(eh + (size_t)kbase * DDIM);
        const float4* sl = (const float4*)(el + (size_t)kbase * DDIM);
        float4* dh = (float4*)EH8;
        float4* dl = (float4*)EL8;
        #pragma unroll
        for (int i = 0; i < 4; ++i) {
            int G = tid + i * 256;            // 0..1023 granules of 16B
            int code = G >> 3, g = G & 7;
            int sw = g ^ (code & 7);
            dh[code * 8 + sw] = sh[G];
            dl[code * 8 + sw] = sl[G];
        }
        if (tid < 128) NRM[tid] = norms[kbase + tid];
    }
    __syncthreads();

    const int wave = tid >> 6;
    const int lane = tid & 63;
    const int lx = lane & 15;   // B col / A row
    const int lk = lane >> 4;   // k-group
    const int pixbase = blockIdx.x * 128 + wave * 32;

    // A fragments (x rows) -> registers
    half8 ah[2][2], al[2][2];
    #pragma unroll
    for (int mt = 0; mt < 2; ++mt) {
        const float* xr = x + (size_t)(pixbase + mt * 16 + lx) * DDIM + lk * 8;
        #pragma unroll
        for (int kh = 0; kh < 2; ++kh) {
            float4 v0 = *(const float4*)(xr + kh * 32);
            float4 v1 = *(const float4*)(xr + kh * 32 + 4);
            half8 hh, ll;
            float vv;
            vv = v0.x; hh[0] = (_Float16)vv; ll[0] = (_Float16)(vv - (float)hh[0]);
            vv = v0.y; hh[1] = (_Float16)vv; ll[1] = (_Float16)(vv - (float)hh[1]);
            vv = v0.z; hh[2] = (_Float16)vv; ll[2] = (_Float16)(vv - (float)hh[2]);
            vv = v0.w; hh[3] = (_Float16)vv; ll[3] = (_Float16)(vv - (float)hh[3]);
            vv = v1.x; hh[4] = (_Float16)vv; ll[4] = (_Float16)(vv - (float)hh[4]);
            vv = v1.y; hh[5] = (_Float16)vv; ll[5] = (_Float16)(vv - (float)hh[5]);
            vv = v1.z; hh[6] = (_Float16)vv; ll[6] = (_Float16)(vv - (float)hh[6]);
            vv = v1.w; hh[7] = (_Float16)vv; ll[7] = (_Float16)(vv - (float)hh[7]);
            ah[mt][kh] = hh;
            al[mt][kh] = ll;
        }
    }

    // running top-2 per slot (mt, r): pixel p_local = mt*16 + lk*4 + r
    float b1[2][4], b2[2][4];
    int   i1[2][4];
    #pragma unroll
    for (int mt = 0; mt < 2; ++mt)
        #pragma unroll
        for (int r = 0; r < 4; ++r) { b1[mt][r] = 3.4e38f; b2[mt][r] = 3.4e38f; i1[mt][r] = 0; }

    #pragma unroll 1
    for (int c = 0; c < 8; ++c) {
        int code = c * 16 + lx;
        const half8* bh = EH8 + code * 8;
        const half8* bl = EL8 + code * 8;
        int sw0 = lk ^ (code & 7);
        int sw1 = (lk + 4) ^ (code & 7);
        half8 bh0 = bh[sw0], bh1 = bh[sw1];
        half8 bl0 = bl[sw0], bl1 = bl[sw1];

        f32x4 acc0 = {0.f, 0.f, 0.f, 0.f};
        f32x4 acc1 = {0.f, 0.f, 0.f, 0.f};
        acc0 = __builtin_amdgcn_mfma_f32_16x16x32_f16(ah[0][0], bh0, acc0, 0, 0, 0);
        acc1 = __builtin_amdgcn_mfma_f32_16x16x32_f16(ah[1][0], bh0, acc1, 0, 0, 0);
        acc0 = __builtin_amdgcn_mfma_f32_16x16x32_f16(ah[0][1], bh1, acc0, 0, 0, 0);
        acc1 = __builtin_amdgcn_mfma_f32_16x16x32_f16(ah[1][1], bh1, acc1, 0, 0, 0);
        acc0 = __builtin_amdgcn_mfma_f32_16x16x32_f16(ah[0][0], bl0, acc0, 0, 0, 0);
        acc1 = __builtin_amdgcn_mfma_f32_16x16x32_f16(ah[1][0], bl0, acc1, 0, 0, 0);
        acc0 = __builtin_amdgcn_mfma_f32_16x16x32_f16(ah[0][1], bl1, acc0, 0, 0, 0);
        acc1 = __builtin_amdgcn_mfma_f32_16x16x32_f16(ah[1][1], bl1, acc1, 0, 0, 0);
        acc0 = __builtin_amdgcn_mfma_f32_16x16x32_f16(al[0][0], bh0, acc0, 0, 0, 0);
        acc1 = __builtin_amdgcn_mfma_f32_16x16x32_f16(al[1][0], bh0, acc1, 0, 0, 0);
        acc0 = __builtin_amdgcn_mfma_f32_16x16x32_f16(al[0][1], bh1, acc0, 0, 0, 0);
        acc1 = __builtin_amdgcn_mfma_f32_16x16x32_f16(al[1][1], bh1, acc1, 0, 0, 0);

        float nrm = NRM[c * 16 + lx];
        int codeg = kbase + c * 16 + lx;
        #pragma unroll
        for (int r = 0; r < 4; ++r) {
            // C layout [m89]: col = lane&15 (code), row = (lane>>4)*4 + r (pixel)
            float d0 = fmaf(-2.0f, acc0[r], nrm);
            bool lt0 = d0 < b1[0][r];
            b2[0][r] = fminf(b2[0][r], fmaxf(b1[0][r], d0));
            b1[0][r] = fminf(b1[0][r], d0);
            i1[0][r] = lt0 ? codeg : i1[0][r];
            float d1 = fmaf(-2.0f, acc1[r], nrm);
            bool lt1 = d1 < b1[1][r];
            b2[1][r] = fminf(b2[1][r], fmaxf(b1[1][r], d1));
            b1[1][r] = fminf(b1[1][r], d1);
            i1[1][r] = lt1 ? codeg : i1[1][r];
        }
    }

    // cross-lane per-pixel top-2 merge via LDS scratch (panels now dead)
    __syncthreads();
    float* S  = (float*)(lds_raw + wave * 6528);  // 3 planes of [32][17] floats
    float* SB1 = S, *SI = S + 544, *SB2 = S + 1088;
    #pragma unroll
    for (int mt = 0; mt < 2; ++mt)
        #pragma unroll
        for (int r = 0; r < 4; ++r) {
            int p = mt * 16 + lk * 4 + r;
            SB1[p * 17 + lx] = b1[mt][r];
            SI [p * 17 + lx] = (float)i1[mt][r];
            SB2[p * 17 + lx] = b2[mt][r];
        }
    __syncthreads();

    if (lane < 32) {
        float gb1 = 3.4e38f, gb2 = 3.4e38f;
        int gi1 = KCODE;
        #pragma unroll
        for (int j = 0; j < 16; ++j) {
            float cb1 = SB1[lane * 17 + j];
            int   ci1 = (int)SI[lane * 17 + j];
            float cb2 = SB2[lane * 17 + j];
            if (cb1 < gb1 || (cb1 == gb1 && ci1 < gi1)) {
                gb2 = fminf(gb1, cb2); gb1 = cb1; gi1 = ci1;
            } else {
                gb2 = fminf(gb2, cb1);
            }
        }
        int pixel = pixbase + lane;
        size_t e = ((size_t)blockIdx.y * NPIX + pixel) * 2;
        cand[e]     = make_float2(gb1, (float)gi1);
        cand[e + 1] = make_float2(gb2, 0.f);
    }
}

// ---------- merge 8 split candidates; flag near-ties for exact fix-up ----------
__global__ void vq_combine8(const float2* __restrict__ cand, float* __restrict__ idxf,
                            int* __restrict__ fixlist, int* __restrict__ fixcount) {
    int n = blockIdx.x * 256 + threadIdx.x;
    float gb1 = 3.4e38f, gb2 = 3.4e38f;
    int gi1 = 0;
    #pragma unroll
    for (int s = 0; s < 8; ++s) {          // ascending s = ascending code range
        size_t e = ((size_t)s * NPIX + n) * 2;
        float2 A = cand[e];
        float2 B = cand[e + 1];
        float cb1 = A.x, cb2 = B.x;
        int ci1 = (int)A.y;
        if (cb1 < gb1) { gb2 = fminf(gb1, cb2); gb1 = cb1; gi1 = ci1; }
        else           { gb2 = fminf(gb2, cb1); }
    }
    idxf[n] = (float)gi1;
    if (gb2 - gb1 < EPS2) {
        int slot = atomicAdd(fixcount, 1);
        if (slot < FIXCAP) fixlist[slot] = n;
    }
}

// ---------- exact fp32 rescan for flagged pixels (first-min-wins) ----------
__global__ __launch_bounds__(64) void vq_fixup(
        const float* __restrict__ x, const float* __restrict__ embT,
        const float* __restrict__ norms, const int* __restrict__ fixlist,
        const int* __restrict__ fixcount, float* __restrict__ idxf) {
    int b = blockIdx.x;
    int cnt = *fixcount;
    if (b >= cnt) return;
    int pixel = fixlist[b];
    int lane = threadIdx.x;

    float xr[64];
    const float4* x4 = (const float4*)(x + (size_t)pixel * DDIM);
    #pragma unroll
    for (int j = 0; j < 16; ++j) {
        float4 v = x4[j];
        xr[j * 4] = v.x; xr[j * 4 + 1] = v.y; xr[j * 4 + 2] = v.z; xr[j * 4 + 3] = v.w;
    }
    float bd = 3.4e38f;
    int bi = 0;
    #pragma unroll 1
    for (int c = 0; c < 16; ++c) {
        int k = lane * 16 + c;               // per-lane ascending idx
        const float4* e4 = (const float4*)(embT + (size_t)k * DDIM);
        float a0 = 0.f, a1 = 0.f, a2 = 0.f, a3 = 0.f;
        #pragma unroll
        for (int j = 0; j < 16; ++j) {
            float4 ev = e4[j];
            a0 = fmaf(xr[j * 4],     ev.x, a0);
            a1 = fmaf(xr[j * 4 + 1], ev.y, a1);
            a2 = fmaf(xr[j * 4 + 2], ev.z, a2);
            a3 = fmaf(xr[j * 4 + 3], ev.w, a3);
        }
        float dd = fmaf(-2.0f, (a0 + a1) + (a2 + a3), norms[k]);
        if (dd < bd) { bd = dd; bi = k; }
    }
    #pragma unroll
    for (int m = 1; m < 64; m <<= 1) {       // lex-min (dist, idx) across 64 lanes
        float od = __shfl_xor(bd, m, 64);
        int   oi = __shfl_xor(bi, m, 64);
        if (od < bd || (od == bd && oi < bi)) { bd = od; bi = oi; }
    }
    if (lane == 0) idxf[pixel] = (float)bi;
}

// ---------- gather quantized + per-block loss partials + histogram ----------
__global__ __launch_bounds__(256) void vq_gather_loss(
        const float* __restrict__ x, const float* __restrict__ embT,
        const float* __restrict__ idxf, float* __restrict__ q,
        float* __restrict__ lossp, int* __restrict__ hist) {
    __shared__ float red[256];
    int i = blockIdx.x * 256 + threadIdx.x;   // over 2097152 float4 units
    int n = i >> 4;
    int j = i & 15;
    int idx = (int)idxf[n];
    if (j == 0) atomicAdd(&hist[idx], 1);
    float4 e4 = ((const float4*)embT)[idx * 16 + j];
    float4 xv = ((const float4*)x)[i];
    ((float4*)q)[i] = e4;
    float dx = e4.x - xv.x, dy = e4.y - xv.y, dz = e4.z - xv.z, dw = e4.w - xv.w;
    red[threadIdx.x] = dx*dx + dy*dy + dz*dz + dw*dw;
    __syncthreads();
    for (int st = 128; st > 0; st >>= 1) {
        if (threadIdx.x < st) red[threadIdx.x] += red[threadIdx.x + st];
        __syncthreads();
    }
    if (threadIdx.x == 0) lossp[blockIdx.x] = red[0];
}

// ---------- one-hot fill: flat 16B-aligned plain float4 stream ----------
// enc base byte ≡ 8 (mod 16) -> enc+2 is 16B aligned. Head/tail 2 floats
// handled by one thread. Aligned float4 segments: 33554431.
__global__ __launch_bounds__(256) void vq_fill(const float* __restrict__ idxf,
                                               float* __restrict__ enc) {
    const long long NSEG = 33554431LL;
    f32x4* base = (f32x4*)(enc + 2);
    long long t0 = (long long)blockIdx.x * 256 + threadIdx.x;
    long long stride = (long long)gridDim.x * 256;
    for (long long s = t0; s < NSEG; s += stride) {
        long long f = 2 + 4 * s;              // flat float index into enc
        int n = (int)(f >> 10);
        int k = (int)(f & 1023);
        int idx0 = (int)idxf[n];
        f32x4 v;
        if (k <= 1020) {
            v.x = (k     == idx0) ? 1.f : 0.f;
            v.y = (k + 1 == idx0) ? 1.f : 0.f;
            v.z = (k + 2 == idx0) ? 1.f : 0.f;
            v.w = (k + 3 == idx0) ? 1.f : 0.f;
        } else {                              // k == 1022: crosses row boundary
            int idx1 = (int)idxf[n + 1];
            v.x = (1022 == idx0) ? 1.f : 0.f;
            v.y = (1023 == idx0) ? 1.f : 0.f;
            v.z = (0    == idx1) ? 1.f : 0.f;
            v.w = (1    == idx1) ? 1.f : 0.f;
        }
        base[s] = v;                          // plain store (L2 write-back)
    }
    if (t0 == 0) {
        int idx0 = (int)idxf[0];
        enc[0] = (idx0 == 0) ? 1.f : 0.f;
        enc[1] = (idx0 == 1) ? 1.f : 0.f;
        int idxL = (int)idxf[NPIX - 1];
        enc[134217726] = (idxL == 1022) ? 1.f : 0.f;
        enc[134217727] = (idxL == 1023) ? 1.f : 0.f;
    }
}

// ---------- finalize: loss sum + perplexity ----------
__global__ void vq_final(const float* __restrict__ lossp, const int* __restrict__ hist,
                         float* __restrict__ out_loss, float* __restrict__ out_perp) {
    __shared__ double red[256];
    int tid = threadIdx.x;
    double s = 0.0;
    for (int i = tid; i < 8192; i += 256) s += (double)lossp[i];
    red[tid] = s;
    __syncthreads();
    for (int st = 128; st > 0; st >>= 1) {
        if (tid < st) red[tid] += red[tid + st];
        __syncthreads();
    }
    if (tid == 0)
        *out_loss = (float)((double)BETA * red[0] / (double)((size_t)NPIX * DDIM));
    __syncthreads();

    double e = 0.0;
    for (int i = tid; i < KCODE; i += 256) {
        float p = (float)hist[i] / (float)NPIX;
        e += (double)(p * logf(p + 1e-10f));
    }
    red[tid] = e;
    __syncthreads();
    for (int st = 128; st > 0; st >>= 1) {
        if (tid < st) red[tid] += red[tid + st];
        __syncthreads();
    }
    if (tid == 0) *out_perp = expf((float)(-red[0]));
}

extern "C" void kernel_launch(void* const* d_in, const int* in_sizes, int n_in,
                              void* d_out, int out_size, void* d_ws, size_t ws_size,
                              hipStream_t stream) {
    const float* x   = (const float*)d_in[0];
    const float* emb = (const float*)d_in[1];
    float* out = (float*)d_out;

    char* ws = (char*)d_ws;
    float* lossp = (float*)ws;              // 8192 floats
    int*   hist  = (int*)(ws + 32768);      // 1024 ints
    float* norms = (float*)(ws + 36864);    // 1024 floats
    float* embT  = (float*)(ws + 40960);    // 65536 floats

    float* q      = out + Q_OFF;
    float* o_loss = out + LOSS_OFF;
    float* o_perp = out + PERP_OFF;
    float* enc    = out + ENC_OFF;
    float* idxf   = out + IDX_OFF;

    // scratch inside the enc region (fully overwritten by vq_fill afterwards)
    float2* cand  = (float2*)(enc + CAND_F);
    __half* eh    = (__half*)(enc + EHT_F);
    __half* el    = (__half*)(enc + ELT_F);
    int* fixlist  = (int*)(enc + FIXLIST_I);
    int* fixcount = (int*)(enc + FIXCOUNT_I);

    (void)hipMemsetAsync(ws + 32768, 0, 4096, stream);          // hist
    (void)hipMemsetAsync((void*)fixcount, 0, 4, stream);        // fix-up counter

    vq_prep<<<256, 256, 0, stream>>>(emb, embT, eh, el);
    vq_norms<<<4, 256, 0, stream>>>(emb, norms);
    vq_argmin_mfma<<<dim3(NPIX / 128, 8), 256, 0, stream>>>(x, eh, el, norms, cand);
    vq_combine8<<<NPIX / 256, 256, 0, stream>>>(cand, idxf, fixlist, fixcount);
    vq_fixup<<<FIXCAP, 64, 0, stream>>>(x, embT, norms, fixlist, fixcount, idxf);
    vq_gather_loss<<<8192, 256, 0, stream>>>(x, embT, idxf, q, lossp, hist);
    vq_fill<<<4096, 256, 0, stream>>>(idxf, enc);
    vq_final<<<1, 256, 0, stream>>>(lossp, hist, o_loss, o_perp);
}

// Round 8
// 257.304 us; speedup vs baseline: 1.5039x; 1.5039x over previous
//
#include <hip/hip_runtime.h>
#include <hip/hip_fp16.h>
#include <math.h>

// Problem constants (x: [32,64,64,64] f32, embedding: [64,1024] f32)
#define NPIX    131072
#define DDIM    64
#define KCODE   1024
#define BETA    0.25f
#define EPS2    4e-3f     // top-2 gap threshold triggering exact fp32 fix-up
#define FIXCAP  2048
#define TAILROW 130944    // NPIX-128: last 128 one-hot rows double as scratch

// d_out layout (float32), in reference return order:
#define Q_OFF    0
#define LOSS_OFF 8388608
#define PERP_OFF 8388609
#define ENC_OFF  8388610   // byte base ≡ 8 (mod 16)
#define IDX_OFF  142606338

// scratch parked in the LAST 128 one-hot rows (float offsets from enc base).
// Fused argmin blocks 0..1022 write only enc[0, TAIL_F); block 1023 writes no
// one-hot; vq_tail rewrites [TAIL_F, end) after fixup. No write/read overlap.
#define TAIL_F     134086656
#define EHT_F      (TAIL_F + 2)       // f16[1024][64] hi  (16B-aligned)
#define ELT_F      (TAIL_F + 32770)   // f16[1024][64] lo  (16B-aligned)
#define FIXLIST_I  (TAIL_F + 65540)   // int pairs {pixel, b1_bits} x FIXCAP
#define FIXDELTA_F (TAIL_F + 69638)   // float[FIXCAP]
#define FIXCOUNT_I (TAIL_F + 71688)   // int

// ws layout (bytes): [0,16384) lossp f32[4096]; [32768,36864) hist int[1024];
//   [36864,40960) norms f32[1024]; [40960,303104) embT f32[1024][64]

typedef _Float16 half8 __attribute__((ext_vector_type(8)));
typedef float    f32x4 __attribute__((ext_vector_type(4)));

// ---------- prep: transpose to embT, f16 hi/lo split, code norms ----------
__global__ void vq_prep(const float* __restrict__ emb, float* __restrict__ embT,
                        _Float16* __restrict__ eh, _Float16* __restrict__ el,
                        float* __restrict__ norms) {
    int b = blockIdx.x;
    if (b < 256) {
        int i = b * 256 + threadIdx.x;    // over 65536
        int d = i >> 10;
        int k = i & 1023;
        float v = emb[i];
        embT[k * DDIM + d] = v;
        _Float16 h = (_Float16)v;
        eh[k * DDIM + d] = h;
        el[k * DDIM + d] = (_Float16)(v - (float)h);
    } else {
        int k = (b - 256) * 256 + threadIdx.x;   // over 1024
        float s = 0.f;
        #pragma unroll 8
        for (int d = 0; d < DDIM; ++d) {
            float v = emb[d * KCODE + k];
            s = fmaf(v, v, s);
        }
        norms[k] = s;
    }
}

// ---------- fused: argmin + one-hot + q gather + loss partials + hist -------
// 1024 blocks x 256 thr; block owns 128 pixels. 8 K-panels staged to LDS;
// after each panel's MFMAs the block zero-fills 1/8 of its 512KB one-hot
// region (write BW overlaps compute). Epilogue: top-2 merge, poke ones,
// gather q rows, per-wave loss partials, near-tie flags (carry approx b1).
__global__ __launch_bounds__(256) void vq_argmin_fused(
        const float* __restrict__ x, const _Float16* __restrict__ eh,
        const _Float16* __restrict__ el, const float* __restrict__ norms,
        const float* __restrict__ embT, float* __restrict__ idxf,
        float* __restrict__ q, float* __restrict__ enc,
        int* __restrict__ hist, float* __restrict__ lossp,
        int* __restrict__ fixlist, int* __restrict__ fixcount) {
    __shared__ char lds_raw[33280];
    half8* EH8 = (half8*)lds_raw;              // [128 codes][8 granules] swizzled
    half8* EL8 = (half8*)(lds_raw + 16384);
    float* NRM = (float*)(lds_raw + 32768);    // [128]

    const int tid   = threadIdx.x;
    const int blkid = blockIdx.x;
    const int wave  = tid >> 6;
    const int lane  = tid & 63;
    const int lx = lane & 15;   // B col / A row
    const int lk = lane >> 4;   // k-group
    const int pixbase = blkid * 128 + wave * 32;

    // A fragments (x rows) -> registers; exact fp32 ||x||^2 partials alongside
    half8 ah[2][2], al[2][2];
    float xp0 = 0.f, xp1 = 0.f;
    #pragma unroll
    for (int mt = 0; mt < 2; ++mt) {
        const float* xr = x + (size_t)(pixbase + mt * 16 + lx) * DDIM + lk * 8;
        float xps = 0.f;
        #pragma unroll
        for (int kh = 0; kh < 2; ++kh) {
            float4 v0 = *(const float4*)(xr + kh * 32);
            float4 v1 = *(const float4*)(xr + kh * 32 + 4);
            xps = fmaf(v0.x, v0.x, xps); xps = fmaf(v0.y, v0.y, xps);
            xps = fmaf(v0.z, v0.z, xps); xps = fmaf(v0.w, v0.w, xps);
            xps = fmaf(v1.x, v1.x, xps); xps = fmaf(v1.y, v1.y, xps);
            xps = fmaf(v1.z, v1.z, xps); xps = fmaf(v1.w, v1.w, xps);
            half8 hh, ll;
            float vv;
            vv = v0.x; hh[0] = (_Float16)vv; ll[0] = (_Float16)(vv - (float)hh[0]);
            vv = v0.y; hh[1] = (_Float16)vv; ll[1] = (_Float16)(vv - (float)hh[1]);
            vv = v0.z; hh[2] = (_Float16)vv; ll[2] = (_Float16)(vv - (float)hh[2]);
            vv = v0.w; hh[3] = (_Float16)vv; ll[3] = (_Float16)(vv - (float)hh[3]);
            vv = v1.x; hh[4] = (_Float16)vv; ll[4] = (_Float16)(vv - (float)hh[4]);
            vv = v1.y; hh[5] = (_Float16)vv; ll[5] = (_Float16)(vv - (float)hh[5]);
            vv = v1.z; hh[6] = (_Float16)vv; ll[6] = (_Float16)(vv - (float)hh[6]);
            vv = v1.w; hh[7] = (_Float16)vv; ll[7] = (_Float16)(vv - (float)hh[7]);
            ah[mt][kh] = hh;
            al[mt][kh] = ll;
        }
        if (mt == 0) xp0 = xps; else xp1 = xps;
    }
    // reduce ||x||^2 over the 4 lk-groups (lanes differing in bits 4,5)
    float xn0 = xp0 + __shfl_xor(xp0, 16); xn0 += __shfl_xor(xn0, 32);
    float xn1 = xp1 + __shfl_xor(xp1, 16); xn1 += __shfl_xor(xn1, 32);

    float b1[2][4], b2[2][4];
    int   i1[2][4];
    #pragma unroll
    for (int mt = 0; mt < 2; ++mt)
        #pragma unroll
        for (int r = 0; r < 4; ++r) { b1[mt][r] = 3.4e38f; b2[mt][r] = 3.4e38f; i1[mt][r] = 0; }

    float* encB = enc + (size_t)blkid * 131072;     // block's one-hot region
    f32x4* zb = (f32x4*)(encB + 2);                 // 16B-aligned (base ≡ 2 mod 4)

    #pragma unroll 1
    for (int t = 0; t < 8; ++t) {
        const int kbase = t * 128;
        __syncthreads();   // previous panel fully consumed
        {
            const float4* sh = (const float4*)(eh + (size_t)kbase * DDIM);
            const float4* sl = (const float4*)(el + (size_t)kbase * DDIM);
            float4* dh = (float4*)EH8;
            float4* dl = (float4*)EL8;
            #pragma unroll
            for (int i = 0; i < 4; ++i) {
                int G = tid + i * 256;
                int code = G >> 3, g = G & 7;
                int sw = g ^ (code & 7);          // XOR granule swizzle
                dh[code * 8 + sw] = sh[G];
                dl[code * 8 + sw] = sl[G];
            }
            if (tid < 128) NRM[tid] = norms[kbase + tid];
        }
        __syncthreads();

        #pragma unroll 1
        for (int c = 0; c < 8; ++c) {
            int code = c * 16 + lx;
            const half8* bhp = EH8 + code * 8;
            const half8* blp = EL8 + code * 8;
            int sw0 = lk ^ (code & 7);
            int sw1 = (lk + 4) ^ (code & 7);
            half8 bh0 = bhp[sw0], bh1 = bhp[sw1];
            half8 bl0 = blp[sw0], bl1 = blp[sw1];

            f32x4 acc0 = {0.f, 0.f, 0.f, 0.f};
            f32x4 acc1 = {0.f, 0.f, 0.f, 0.f};
            acc0 = __builtin_amdgcn_mfma_f32_16x16x32_f16(ah[0][0], bh0, acc0, 0, 0, 0);
            acc1 = __builtin_amdgcn_mfma_f32_16x16x32_f16(ah[1][0], bh0, acc1, 0, 0, 0);
            acc0 = __builtin_amdgcn_mfma_f32_16x16x32_f16(ah[0][1], bh1, acc0, 0, 0, 0);
            acc1 = __builtin_amdgcn_mfma_f32_16x16x32_f16(ah[1][1], bh1, acc1, 0, 0, 0);
            acc0 = __builtin_amdgcn_mfma_f32_16x16x32_f16(ah[0][0], bl0, acc0, 0, 0, 0);
            acc1 = __builtin_amdgcn_mfma_f32_16x16x32_f16(ah[1][0], bl0, acc1, 0, 0, 0);
            acc0 = __builtin_amdgcn_mfma_f32_16x16x32_f16(ah[0][1], bl1, acc0, 0, 0, 0);
            acc1 = __builtin_amdgcn_mfma_f32_16x16x32_f16(ah[1][1], bl1, acc1, 0, 0, 0);
            acc0 = __builtin_amdgcn_mfma_f32_16x16x32_f16(al[0][0], bh0, acc0, 0, 0, 0);
            acc1 = __builtin_amdgcn_mfma_f32_16x16x32_f16(al[1][0], bh0, acc1, 0, 0, 0);
            acc0 = __builtin_amdgcn_mfma_f32_16x16x32_f16(al[0][1], bh1, acc0, 0, 0, 0);
            acc1 = __builtin_amdgcn_mfma_f32_16x16x32_f16(al[1][1], bh1, acc1, 0, 0, 0);

            float nrm = NRM[c * 16 + lx];
            int codeg = kbase + c * 16 + lx;
            #pragma unroll
            for (int r = 0; r < 4; ++r) {
                // C layout [m89]: col = lane&15 (code), row = (lane>>4)*4 + r (pixel)
                float d0 = fmaf(-2.0f, acc0[r], nrm);
                bool lt0 = d0 < b1[0][r];
                b2[0][r] = fminf(b2[0][r], fmaxf(b1[0][r], d0));
                b1[0][r] = fminf(b1[0][r], d0);
                i1[0][r] = lt0 ? codeg : i1[0][r];
                float d1 = fmaf(-2.0f, acc1[r], nrm);
                bool lt1 = d1 < b1[1][r];
                b2[1][r] = fminf(b2[1][r], fmaxf(b1[1][r], d1));
                b1[1][r] = fminf(b1[1][r], d1);
                i1[1][r] = lt1 ? codeg : i1[1][r];
            }
        }

        // zero-fill 1/8 of this block's one-hot region (overlaps next staging)
        if (blkid != 1023) {
            f32x4 z = {0.f, 0.f, 0.f, 0.f};
            #pragma unroll
            for (int it = 0; it < 16; ++it) {
                int fi = t * 4096 + it * 256 + tid;
                if (fi < 32767) zb[fi] = z;
            }
            if (t == 7 && tid == 0) {
                encB[0] = 0.f; encB[1] = 0.f;
                encB[131070] = 0.f; encB[131071] = 0.f;
            }
        }
    }

    // cross-lane per-pixel top-2 merge via LDS scratch (panels dead)
    __syncthreads();
    float* S  = (float*)(lds_raw + wave * 6528);  // 3 planes of [32][17] floats
    float* SB1 = S, *SI = S + 544, *SB2 = S + 1088;
    int* idx_lds = (int*)(lds_raw + 26112);       // [128]
    #pragma unroll
    for (int mt = 0; mt < 2; ++mt)
        #pragma unroll
        for (int r = 0; r < 4; ++r) {
            int p = mt * 16 + lk * 4 + r;
            SB1[p * 17 + lx] = b1[mt][r];
            SI [p * 17 + lx] = (float)i1[mt][r];
            SB2[p * 17 + lx] = b2[mt][r];
        }
    __syncthreads();

    // ||x||^2 for pixel `lane` (donor lane lane&15 holds both mt values)
    float xf0 = __shfl(xn0, lane & 15);
    float xf1 = __shfl(xn1, lane & 15);
    float xf  = (lane >> 4) ? xf1 : xf0;   // valid for lane<32

    float gb1 = 3.4e38f, gb2 = 3.4e38f;
    int gi1 = 0;
    if (lane < 32) {
        gi1 = KCODE;
        #pragma unroll
        for (int j = 0; j < 16; ++j) {
            float cb1 = SB1[lane * 17 + j];
            int   ci1 = (int)SI[lane * 17 + j];
            float cb2 = SB2[lane * 17 + j];
            if (cb1 < gb1 || (cb1 == gb1 && ci1 < gi1)) {
                gb2 = fminf(gb1, cb2); gb1 = cb1; gi1 = ci1;
            } else {
                gb2 = fminf(gb2, cb1);
            }
        }
        int pixel = pixbase + lane;
        idxf[pixel] = (float)gi1;
        idx_lds[wave * 32 + lane] = gi1;
        atomicAdd(&hist[gi1], 1);
        if (blkid != 1023) enc[(size_t)pixel * 1024 + gi1] = 1.f;  // zeros done
        if (gb2 - gb1 < EPS2) {
            int slot = atomicAdd(fixcount, 1);
            if (slot < FIXCAP) {
                fixlist[2 * slot]     = pixel;
                fixlist[2 * slot + 1] = __float_as_int(gb1);
            }
        }
    }

    // per-wave loss partial: sum of (b1 + ||x||^2) over 32 pixels
    float sq = (lane < 32) ? (gb1 + xf) : 0.f;
    #pragma unroll
    for (int m = 1; m < 64; m <<= 1) sq += __shfl_xor(sq, m);
    if (lane == 0) lossp[blkid * 4 + wave] = sq;

    // q gather: 128 rows x 16 float4 from embT
    __syncthreads();
    const f32x4* eT4 = (const f32x4*)embT;
    f32x4* q4 = (f32x4*)q;
    #pragma unroll
    for (int it = 0; it < 8; ++it) {
        int i = it * 256 + tid;
        int r = i >> 4, j = i & 15;
        int idx = idx_lds[r];
        q4[((size_t)blkid * 128 + r) * 16 + j] = eT4[idx * 16 + j];
    }
}

// ---------- exact fp32 rescan + patch for flagged pixels ----------
__global__ __launch_bounds__(64) void vq_fixup(
        const float* __restrict__ x, const float* __restrict__ embT,
        const float* __restrict__ norms, const int* __restrict__ fixlist,
        const int* __restrict__ fixcount, float* __restrict__ idxf,
        float* __restrict__ q, float* __restrict__ enc,
        int* __restrict__ hist, float* __restrict__ fixdelta) {
    int cnt = *fixcount;
    if (cnt > FIXCAP) cnt = FIXCAP;
    int b = blockIdx.x;
    if (b >= cnt) return;
    int pixel = fixlist[2 * b];
    float b1old = __int_as_float(fixlist[2 * b + 1]);
    int lane = threadIdx.x;

    float xr[64];
    const float4* x4 = (const float4*)(x + (size_t)pixel * DDIM);
    #pragma unroll
    for (int j = 0; j < 16; ++j) {
        float4 v = x4[j];
        xr[j * 4] = v.x; xr[j * 4 + 1] = v.y; xr[j * 4 + 2] = v.z; xr[j * 4 + 3] = v.w;
    }
    float bd = 3.4e38f;
    int bi = 0;
    #pragma unroll 1
    for (int c = 0; c < 16; ++c) {
        int k = lane * 16 + c;               // per-lane ascending idx
        const float4* e4 = (const float4*)(embT + (size_t)k * DDIM);
        float a0 = 0.f, a1 = 0.f, a2 = 0.f, a3 = 0.f;
        #pragma unroll
        for (int j = 0; j < 16; ++j) {
            float4 ev = e4[j];
            a0 = fmaf(xr[j * 4],     ev.x, a0);
            a1 = fmaf(xr[j * 4 + 1], ev.y, a1);
            a2 = fmaf(xr[j * 4 + 2], ev.z, a2);
            a3 = fmaf(xr[j * 4 + 3], ev.w, a3);
        }
        float dd = fmaf(-2.0f, (a0 + a1) + (a2 + a3), norms[k]);
        if (dd < bd) { bd = dd; bi = k; }
    }
    #pragma unroll
    for (int m = 1; m < 64; m <<= 1) {       // lex-min (dist, idx) across 64 lanes
        float od = __shfl_xor(bd, m, 64);
        int   oi = __shfl_xor(bi, m, 64);
        if (od < bd || (od == bd && oi < bi)) { bd = od; bi = oi; }
    }
    // q row patch (exact fp32 codeword), all 64 lanes
    q[(size_t)pixel * DDIM + lane] = embT[(size_t)bi * DDIM + lane];
    if (lane == 0) {
        int old = (int)idxf[pixel];
        idxf[pixel] = (float)bi;
        fixdelta[b] = bd - b1old;            // loss correction (||x||^2 cancels)
        if (bi != old) {
            atomicAdd(&hist[old], -1);
            atomicAdd(&hist[bi], 1);
            if (pixel < TAILROW) {           // tail rows handled by vq_tail
                enc[(size_t)pixel * 1024 + old] = 0.f;
                enc[(size_t)pixel * 1024 + bi]  = 1.f;
            }
        }
    }
}

// ---------- tail: one-hot for the last 128 rows (ex-scratch), final idx -----
__global__ void vq_tail(const float* __restrict__ idxf, float* __restrict__ enc) {
    int r = blockIdx.x;                 // 0..127
    int pixel = TAILROW + r;
    int idx = (int)idxf[pixel];
    size_t base = (size_t)pixel * 1024;
    int t = threadIdx.x;
    if (t < 255) {
        int k = 4 * t + 2;
        f32x4 v;
        v.x = (k     == idx) ? 1.f : 0.f;
        v.y = (k + 1 == idx) ? 1.f : 0.f;
        v.z = (k + 2 == idx) ? 1.f : 0.f;
        v.w = (k + 3 == idx) ? 1.f : 0.f;
        *(f32x4*)(enc + base + k) = v;
    } else {
        enc[base]        = (idx == 0)    ? 1.f : 0.f;
        enc[base + 1]    = (idx == 1)    ? 1.f : 0.f;
        enc[base + 1022] = (idx == 1022) ? 1.f : 0.f;
        enc[base + 1023] = (idx == 1023) ? 1.f : 0.f;
    }
}

// ---------- finalize: loss sum (+ ordered fix deltas) + perplexity ----------
__global__ void vq_final(const float* __restrict__ lossp, const int* __restrict__ hist,
                         const float* __restrict__ fixdelta,
                         const int* __restrict__ fixcount,
                         float* __restrict__ out_loss, float* __restrict__ out_perp) {
    __shared__ double red[256];
    int tid = threadIdx.x;
    double s = 0.0;
    for (int i = tid; i < 4096; i += 256) s += (double)lossp[i];
    red[tid] = s;
    __syncthreads();
    for (int st = 128; st > 0; st >>= 1) {
        if (tid < st) red[tid] += red[tid + st];
        __syncthreads();
    }
    if (tid == 0) {
        int cnt = *fixcount;
        if (cnt > FIXCAP) cnt = FIXCAP;
        double d = red[0];
        for (int i = 0; i < cnt; ++i) d += (double)fixdelta[i];
        *out_loss = (float)((double)BETA * d / (double)((size_t)NPIX * DDIM));
    }
    __syncthreads();

    double e = 0.0;
    for (int i = tid; i < KCODE; i += 256) {
        float p = (float)hist[i] / (float)NPIX;
        e += (double)(p * logf(p + 1e-10f));
    }
    red[tid] = e;
    __syncthreads();
    for (int st = 128; st > 0; st >>= 1) {
        if (tid < st) red[tid] += red[tid + st];
        __syncthreads();
    }
    if (tid == 0) *out_perp = expf((float)(-red[0]));
}

extern "C" void kernel_launch(void* const* d_in, const int* in_sizes, int n_in,
                              void* d_out, int out_size, void* d_ws, size_t ws_size,
                              hipStream_t stream) {
    const float* x   = (const float*)d_in[0];
    const float* emb = (const float*)d_in[1];
    float* out = (float*)d_out;

    char* ws = (char*)d_ws;
    float* lossp = (float*)ws;              // 4096 floats
    int*   hist  = (int*)(ws + 32768);      // 1024 ints
    float* norms = (float*)(ws + 36864);    // 1024 floats
    float* embT  = (float*)(ws + 40960);    // 65536 floats

    float* q      = out + Q_OFF;
    float* o_loss = out + LOSS_OFF;
    float* o_perp = out + PERP_OFF;
    float* enc    = out + ENC_OFF;
    float* idxf   = out + IDX_OFF;

    // scratch in the last 128 one-hot rows (rewritten by vq_tail at the end)
    _Float16* eh    = (_Float16*)(enc + EHT_F);
    _Float16* el    = (_Float16*)(enc + ELT_F);
    int* fixlist    = (int*)(enc + FIXLIST_I);
    float* fixdelta = (float*)(enc + FIXDELTA_F);
    int* fixcount   = (int*)(enc + FIXCOUNT_I);

    (void)hipMemsetAsync(ws + 32768, 0, 4096, stream);     // hist
    (void)hipMemsetAsync((void*)fixcount, 0, 4, stream);   // fix-up counter

    vq_prep<<<260, 256, 0, stream>>>(emb, embT, eh, el, norms);
    vq_argmin_fused<<<1024, 256, 0, stream>>>(x, eh, el, norms, embT, idxf, q,
                                              enc, hist, lossp, fixlist, fixcount);
    vq_fixup<<<FIXCAP, 64, 0, stream>>>(x, embT, norms, fixlist, fixcount,
                                        idxf, q, enc, hist, fixdelta);
    vq_tail<<<128, 256, 0, stream>>>(idxf, enc);
    vq_final<<<1, 256, 0, stream>>>(lossp, hist, fixdelta, fixcount, o_loss, o_perp);
}

// Round 9
// 206.064 us; speedup vs baseline: 1.8779x; 1.2487x over previous
//
#include <hip/hip_runtime.h>
#include <hip/hip_fp16.h>
#include <math.h>

// Problem constants (x: [32,64,64,64] f32, embedding: [64,1024] f32)
#define NPIX    131072
#define DDIM    64
#define KCODE   1024
#define BETA    0.25f
#define EPS2    4e-3f     // top-2 gap threshold triggering exact fp32 fix-up
#define FIXCAP  2048
#define TAILROW 130944    // NPIX-128: last 128 one-hot rows double as scratch

// d_out layout (float32), in reference return order:
#define Q_OFF    0
#define LOSS_OFF 8388608
#define PERP_OFF 8388609
#define ENC_OFF  8388610   // byte base ≡ 8 (mod 16)
#define IDX_OFF  142606338

// scratch parked in the LAST 128 one-hot rows (float offsets from enc base).
// Fused blocks 0..1022 write only their own rows; block 1023 (the tail rows)
// writes no one-hot; vq_tail rewrites them AFTER vq_final consumed fixdelta.
#define TAIL_F     134086656
#define EHS_F      (TAIL_F + 2)       // f16[8 panels][128 codes][8 gran][8] PRE-SWIZZLED
#define ELS_F      (TAIL_F + 32770)   // same for lo part
#define FIXLIST_I  (TAIL_F + 65540)   // int pairs {pixel, b1_bits} x FIXCAP
#define FIXDELTA_F (TAIL_F + 69638)   // float[FIXCAP]
#define FIXCOUNT_I (TAIL_F + 71688)   // int

// ws layout (bytes): [0,16384) lossp f32[4096]; [32768,36864) hist int[1024];
//   [36864,40960) norms f32[1024]; [40960,303104) embT f32[1024][64]

typedef _Float16 half8 __attribute__((ext_vector_type(8)));
typedef float    f32x4 __attribute__((ext_vector_type(4)));
typedef __attribute__((address_space(3))) void       lds_void_t;
typedef __attribute__((address_space(1))) const void g_void_t;

// ---------- prep: transpose to embT, f16 hi/lo split (pre-swizzled), norms ---
__global__ void vq_prep(const float* __restrict__ emb, float* __restrict__ embT,
                        _Float16* __restrict__ ehs, _Float16* __restrict__ els,
                        float* __restrict__ norms) {
    int b = blockIdx.x;
    if (b < 256) {
        int i = b * 256 + threadIdx.x;    // over 65536
        int d = i >> 10;
        int k = i & 1023;
        float v = emb[i];
        embT[k * DDIM + d] = v;
        _Float16 h = (_Float16)v;
        _Float16 l = (_Float16)(v - (float)h);
        // pre-swizzled panel layout: global slot codeP*8 + (g ^ (code&7))
        int panel = k >> 7, codeP = k & 127;
        int sw = (d >> 3) ^ (k & 7);
        int fi = panel * 8192 + codeP * 64 + sw * 8 + (d & 7);
        ehs[fi] = h;
        els[fi] = l;
    } else {
        int k = (b - 256) * 256 + threadIdx.x;   // over 1024
        float s = 0.f;
        #pragma unroll 8
        for (int d = 0; d < DDIM; ++d) {
            float v = emb[d * KCODE + k];
            s = fmaf(v, v, s);
        }
        norms[k] = s;
    }
}

// ---------- fused: argmin + one-hot + q gather + loss partials + hist -------
// 1024 blocks x 256 thr; block owns 128 pixels. 8 K-panels DMA'd to LDS via
// global_load_lds (pre-swizzled source, linear dest). Raw s_barrier + counted
// vmcnt(16): zero-fill stores stay in flight across barriers and drain under
// the MFMA phase (never vmcnt(0) in the loop).
__global__ __launch_bounds__(256) void vq_argmin_fused(
        const float* __restrict__ x, const _Float16* __restrict__ ehs,
        const _Float16* __restrict__ els, const float* __restrict__ norms,
        const float* __restrict__ embT, float* __restrict__ idxf,
        float* __restrict__ q, float* __restrict__ enc,
        int* __restrict__ hist, float* __restrict__ lossp,
        int* __restrict__ fixlist, int* __restrict__ fixcount) {
    __shared__ __align__(16) char lds_raw[36864];
    half8* EH8   = (half8*)lds_raw;             // [128 codes][8 granules] swizzled
    half8* EL8   = (half8*)(lds_raw + 16384);
    float* NRMa  = (float*)(lds_raw + 32768);   // [1024] all norms

    const int tid   = threadIdx.x;
    const int blkid = blockIdx.x;
    const int wave  = tid >> 6;
    const int lane  = tid & 63;
    const int lx = lane & 15;   // B col / A row
    const int lk = lane >> 4;   // k-group
    const int pixbase = blkid * 128 + wave * 32;

    // stage ALL norms once (4KB LDS)
    #pragma unroll
    for (int i = 0; i < 4; ++i) NRMa[tid + i * 256] = norms[tid + i * 256];

    // A fragments (x rows) -> registers; exact fp32 ||x||^2 partials alongside
    half8 ah[2][2], al[2][2];
    float xp0 = 0.f, xp1 = 0.f;
    #pragma unroll
    for (int mt = 0; mt < 2; ++mt) {
        const float* xr = x + (size_t)(pixbase + mt * 16 + lx) * DDIM + lk * 8;
        float xps = 0.f;
        #pragma unroll
        for (int kh = 0; kh < 2; ++kh) {
            float4 v0 = *(const float4*)(xr + kh * 32);
            float4 v1 = *(const float4*)(xr + kh * 32 + 4);
            xps = fmaf(v0.x, v0.x, xps); xps = fmaf(v0.y, v0.y, xps);
            xps = fmaf(v0.z, v0.z, xps); xps = fmaf(v0.w, v0.w, xps);
            xps = fmaf(v1.x, v1.x, xps); xps = fmaf(v1.y, v1.y, xps);
            xps = fmaf(v1.z, v1.z, xps); xps = fmaf(v1.w, v1.w, xps);
            half8 hh, ll;
            float vv;
            vv = v0.x; hh[0] = (_Float16)vv; ll[0] = (_Float16)(vv - (float)hh[0]);
            vv = v0.y; hh[1] = (_Float16)vv; ll[1] = (_Float16)(vv - (float)hh[1]);
            vv = v0.z; hh[2] = (_Float16)vv; ll[2] = (_Float16)(vv - (float)hh[2]);
            vv = v0.w; hh[3] = (_Float16)vv; ll[3] = (_Float16)(vv - (float)hh[3]);
            vv = v1.x; hh[4] = (_Float16)vv; ll[4] = (_Float16)(vv - (float)hh[4]);
            vv = v1.y; hh[5] = (_Float16)vv; ll[5] = (_Float16)(vv - (float)hh[5]);
            vv = v1.z; hh[6] = (_Float16)vv; ll[6] = (_Float16)(vv - (float)hh[6]);
            vv = v1.w; hh[7] = (_Float16)vv; ll[7] = (_Float16)(vv - (float)hh[7]);
            ah[mt][kh] = hh;
            al[mt][kh] = ll;
        }
        if (mt == 0) xp0 = xps; else xp1 = xps;
    }
    float xn0 = xp0 + __shfl_xor(xp0, 16); xn0 += __shfl_xor(xn0, 32);
    float xn1 = xp1 + __shfl_xor(xp1, 16); xn1 += __shfl_xor(xn1, 32);

    float b1[2][4], b2[2][4];
    int   i1[2][4];
    #pragma unroll
    for (int mt = 0; mt < 2; ++mt)
        #pragma unroll
        for (int r = 0; r < 4; ++r) { b1[mt][r] = 3.4e38f; b2[mt][r] = 3.4e38f; i1[mt][r] = 0; }

    float* encB = enc + (size_t)blkid * 131072;     // block's one-hot region
    f32x4* zb = (f32x4*)(encB + 2);                 // 16B-aligned

    __syncthreads();   // NRM staged; full drain -> clean vmcnt baseline

    #pragma unroll 1
    for (int t = 0; t < 8; ++t) {
        __builtin_amdgcn_sched_barrier(0);
        __builtin_amdgcn_s_barrier();               // all waves done with panel t-1
        __builtin_amdgcn_sched_barrier(0);
        {
            const char* gH = (const char*)ehs + (t << 14) + (tid << 4);
            const char* gL = (const char*)els + (t << 14) + (tid << 4);
            char* lH = &lds_raw[wave << 10];
            char* lL = &lds_raw[16384 + (wave << 10)];
            #pragma unroll
            for (int i = 0; i < 4; ++i) {
                __builtin_amdgcn_global_load_lds((g_void_t*)(gH + (i << 12)),
                                                 (lds_void_t*)(lH + (i << 12)), 16, 0, 0);
                __builtin_amdgcn_global_load_lds((g_void_t*)(gL + (i << 12)),
                                                 (lds_void_t*)(lL + (i << 12)), 16, 0, 0);
            }
        }
        __builtin_amdgcn_sched_barrier(0);
        if (blkid != 1023) {
            // zero-fill chunk t (16 stores/thread) issued AFTER the 8 loads:
            // vmcnt(16) waits loads (and last iter's stores), leaves these 16
            // newest stores in flight across the barrier.
            f32x4 z = {0.f, 0.f, 0.f, 0.f};
            #pragma unroll
            for (int it = 0; it < 16; ++it) {
                int fi = t * 4096 + it * 256 + tid;
                if (fi < 32767) zb[fi] = z;
            }
            asm volatile("s_waitcnt vmcnt(16)" ::: "memory");
        } else {
            asm volatile("s_waitcnt vmcnt(0)" ::: "memory");
        }
        __builtin_amdgcn_sched_barrier(0);
        __builtin_amdgcn_s_barrier();               // panel t resident for all
        __builtin_amdgcn_sched_barrier(0);

        const int kbase = t * 128;
        #pragma unroll 1
        for (int c = 0; c < 8; ++c) {
            int code = c * 16 + lx;
            const half8* bhp = EH8 + code * 8;
            const half8* blp = EL8 + code * 8;
            int sw0 = lk ^ (code & 7);
            int sw1 = (lk + 4) ^ (code & 7);
            half8 bh0 = bhp[sw0], bh1 = bhp[sw1];
            half8 bl0 = blp[sw0], bl1 = blp[sw1];

            f32x4 acc0 = {0.f, 0.f, 0.f, 0.f};
            f32x4 acc1 = {0.f, 0.f, 0.f, 0.f};
            acc0 = __builtin_amdgcn_mfma_f32_16x16x32_f16(ah[0][0], bh0, acc0, 0, 0, 0);
            acc1 = __builtin_amdgcn_mfma_f32_16x16x32_f16(ah[1][0], bh0, acc1, 0, 0, 0);
            acc0 = __builtin_amdgcn_mfma_f32_16x16x32_f16(ah[0][1], bh1, acc0, 0, 0, 0);
            acc1 = __builtin_amdgcn_mfma_f32_16x16x32_f16(ah[1][1], bh1, acc1, 0, 0, 0);
            acc0 = __builtin_amdgcn_mfma_f32_16x16x32_f16(ah[0][0], bl0, acc0, 0, 0, 0);
            acc1 = __builtin_amdgcn_mfma_f32_16x16x32_f16(ah[1][0], bl0, acc1, 0, 0, 0);
            acc0 = __builtin_amdgcn_mfma_f32_16x16x32_f16(ah[0][1], bl1, acc0, 0, 0, 0);
            acc1 = __builtin_amdgcn_mfma_f32_16x16x32_f16(ah[1][1], bl1, acc1, 0, 0, 0);
            acc0 = __builtin_amdgcn_mfma_f32_16x16x32_f16(al[0][0], bh0, acc0, 0, 0, 0);
            acc1 = __builtin_amdgcn_mfma_f32_16x16x32_f16(al[1][0], bh0, acc1, 0, 0, 0);
            acc0 = __builtin_amdgcn_mfma_f32_16x16x32_f16(al[0][1], bh1, acc0, 0, 0, 0);
            acc1 = __builtin_amdgcn_mfma_f32_16x16x32_f16(al[1][1], bh1, acc1, 0, 0, 0);

            float nrm = NRMa[kbase + c * 16 + lx];
            int codeg = kbase + c * 16 + lx;
            #pragma unroll
            for (int r = 0; r < 4; ++r) {
                // C layout [m89]: col = lane&15 (code), row = (lane>>4)*4 + r (pixel)
                float d0 = fmaf(-2.0f, acc0[r], nrm);
                bool lt0 = d0 < b1[0][r];
                b2[0][r] = fminf(b2[0][r], fmaxf(b1[0][r], d0));
                b1[0][r] = fminf(b1[0][r], d0);
                i1[0][r] = lt0 ? codeg : i1[0][r];
                float d1 = fmaf(-2.0f, acc1[r], nrm);
                bool lt1 = d1 < b1[1][r];
                b2[1][r] = fminf(b2[1][r], fmaxf(b1[1][r], d1));
                b1[1][r] = fminf(b1[1][r], d1);
                i1[1][r] = lt1 ? codeg : i1[1][r];
            }
        }
        __builtin_amdgcn_sched_barrier(0);
    }

    // head/tail singles of this block's region
    if (blkid != 1023 && tid == 0) {
        encB[0] = 0.f; encB[1] = 0.f;
        encB[131070] = 0.f; encB[131071] = 0.f;
    }
    asm volatile("s_waitcnt vmcnt(0)" ::: "memory");   // all zeros landed
    __syncthreads();

    // cross-lane per-pixel top-2 merge via LDS scratch (panels dead)
    float* S  = (float*)(lds_raw + wave * 6528);  // 3 planes of [32][17] floats
    float* SB1 = S, *SI = S + 544, *SB2 = S + 1088;
    int* idx_lds = (int*)(lds_raw + 26112);       // [128]
    #pragma unroll
    for (int mt = 0; mt < 2; ++mt)
        #pragma unroll
        for (int r = 0; r < 4; ++r) {
            int p = mt * 16 + lk * 4 + r;
            SB1[p * 17 + lx] = b1[mt][r];
            SI [p * 17 + lx] = (float)i1[mt][r];
            SB2[p * 17 + lx] = b2[mt][r];
        }
    __syncthreads();

    // ||x||^2 for pixel `lane` (donor lane lane&15 holds both mt values)
    float xf0 = __shfl(xn0, lane & 15);
    float xf1 = __shfl(xn1, lane & 15);
    float xf  = (lane >> 4) ? xf1 : xf0;   // valid for lane<32

    float gb1 = 3.4e38f, gb2 = 3.4e38f;
    int gi1 = 0;
    if (lane < 32) {
        gi1 = KCODE;
        #pragma unroll
        for (int j = 0; j < 16; ++j) {
            float cb1 = SB1[lane * 17 + j];
            int   ci1 = (int)SI[lane * 17 + j];
            float cb2 = SB2[lane * 17 + j];
            if (cb1 < gb1 || (cb1 == gb1 && ci1 < gi1)) {
                gb2 = fminf(gb1, cb2); gb1 = cb1; gi1 = ci1;
            } else {
                gb2 = fminf(gb2, cb1);
            }
        }
        int pixel = pixbase + lane;
        idxf[pixel] = (float)gi1;
        idx_lds[wave * 32 + lane] = gi1;
        atomicAdd(&hist[gi1], 1);
        if (blkid != 1023) enc[(size_t)pixel * 1024 + gi1] = 1.f;  // zeros done
        if (gb2 - gb1 < EPS2) {
            int slot = atomicAdd(fixcount, 1);
            if (slot < FIXCAP) {
                fixlist[2 * slot]     = pixel;
                fixlist[2 * slot + 1] = __float_as_int(gb1);
            }
        }
    }

    // per-wave loss partial: sum of (b1 + ||x||^2) over 32 pixels
    float sq = (lane < 32) ? (gb1 + xf) : 0.f;
    #pragma unroll
    for (int m = 1; m < 64; m <<= 1) sq += __shfl_xor(sq, m);
    if (lane == 0) lossp[blkid * 4 + wave] = sq;

    // q gather: 128 rows x 16 float4 from embT
    __syncthreads();
    const f32x4* eT4 = (const f32x4*)embT;
    f32x4* q4 = (f32x4*)q;
    #pragma unroll
    for (int it = 0; it < 8; ++it) {
        int i = it * 256 + tid;
        int r = i >> 4, j = i & 15;
        int idx = idx_lds[r];
        q4[((size_t)blkid * 128 + r) * 16 + j] = eT4[idx * 16 + j];
    }
}

// ---------- exact fp32 rescan + patch for flagged pixels ----------
__global__ __launch_bounds__(64) void vq_fixup(
        const float* __restrict__ x, const float* __restrict__ embT,
        const float* __restrict__ norms, const int* __restrict__ fixlist,
        const int* __restrict__ fixcount, float* __restrict__ idxf,
        float* __restrict__ q, float* __restrict__ enc,
        int* __restrict__ hist, float* __restrict__ fixdelta) {
    int cnt = *fixcount;
    if (cnt > FIXCAP) cnt = FIXCAP;
    int b = blockIdx.x;
    if (b >= cnt) return;
    int pixel = fixlist[2 * b];
    float b1old = __int_as_float(fixlist[2 * b + 1]);
    int lane = threadIdx.x;

    float xr[64];
    const float4* x4 = (const float4*)(x + (size_t)pixel * DDIM);
    #pragma unroll
    for (int j = 0; j < 16; ++j) {
        float4 v = x4[j];
        xr[j * 4] = v.x; xr[j * 4 + 1] = v.y; xr[j * 4 + 2] = v.z; xr[j * 4 + 3] = v.w;
    }
    float bd = 3.4e38f;
    int bi = 0;
    #pragma unroll 1
    for (int c = 0; c < 16; ++c) {
        int k = lane * 16 + c;               // per-lane ascending idx
        const float4* e4 = (const float4*)(embT + (size_t)k * DDIM);
        float a0 = 0.f, a1 = 0.f, a2 = 0.f, a3 = 0.f;
        #pragma unroll
        for (int j = 0; j < 16; ++j) {
            float4 ev = e4[j];
            a0 = fmaf(xr[j * 4],     ev.x, a0);
            a1 = fmaf(xr[j * 4 + 1], ev.y, a1);
            a2 = fmaf(xr[j * 4 + 2], ev.z, a2);
            a3 = fmaf(xr[j * 4 + 3], ev.w, a3);
        }
        float dd = fmaf(-2.0f, (a0 + a1) + (a2 + a3), norms[k]);
        if (dd < bd) { bd = dd; bi = k; }
    }
    #pragma unroll
    for (int m = 1; m < 64; m <<= 1) {       // lex-min (dist, idx) across 64 lanes
        float od = __shfl_xor(bd, m, 64);
        int   oi = __shfl_xor(bi, m, 64);
        if (od < bd || (od == bd && oi < bi)) { bd = od; bi = oi; }
    }
    q[(size_t)pixel * DDIM + lane] = embT[(size_t)bi * DDIM + lane];
    if (lane == 0) {
        int old = (int)idxf[pixel];
        idxf[pixel] = (float)bi;
        fixdelta[b] = bd - b1old;            // loss correction (||x||^2 cancels)
        if (bi != old) {
            atomicAdd(&hist[old], -1);
            atomicAdd(&hist[bi], 1);
            if (pixel < TAILROW) {           // tail rows handled by vq_tail
                enc[(size_t)pixel * 1024 + old] = 0.f;
                enc[(size_t)pixel * 1024 + bi]  = 1.f;
            }
        }
    }
}

// ---------- finalize: loss sum (+ fix deltas) + perplexity ----------
// MUST run before vq_tail (fixdelta/fixcount live in the tail scratch rows).
__global__ void vq_final(const float* __restrict__ lossp, const int* __restrict__ hist,
                         const float* __restrict__ fixdelta,
                         const int* __restrict__ fixcount,
                         float* __restrict__ out_loss, float* __restrict__ out_perp) {
    __shared__ double red[256];
    int tid = threadIdx.x;
    double s = 0.0;
    for (int i = tid; i < 4096; i += 256) s += (double)lossp[i];
    red[tid] = s;
    __syncthreads();
    for (int st = 128; st > 0; st >>= 1) {
        if (tid < st) red[tid] += red[tid + st];
        __syncthreads();
    }
    if (tid == 0) {
        int cnt = *fixcount;
        if (cnt > FIXCAP) cnt = FIXCAP;
        double d = red[0];
        for (int i = 0; i < cnt; ++i) d += (double)fixdelta[i];
        *out_loss = (float)((double)BETA * d / (double)((size_t)NPIX * DDIM));
    }
    __syncthreads();

    double e = 0.0;
    for (int i = tid; i < KCODE; i += 256) {
        float p = (float)hist[i] / (float)NPIX;
        e += (double)(p * logf(p + 1e-10f));
    }
    red[tid] = e;
    __syncthreads();
    for (int st = 128; st > 0; st >>= 1) {
        if (tid < st) red[tid] += red[tid + st];
        __syncthreads();
    }
    if (tid == 0) *out_perp = expf((float)(-red[0]));
}

// ---------- tail: one-hot for the last 128 rows (ex-scratch) ----------
__global__ void vq_tail(const float* __restrict__ idxf, float* __restrict__ enc) {
    int r = blockIdx.x;                 // 0..127
    int pixel = TAILROW + r;
    int idx = (int)idxf[pixel];
    size_t base = (size_t)pixel * 1024;
    int t = threadIdx.x;
    if (t < 255) {
        int k = 4 * t + 2;
        f32x4 v;
        v.x = (k     == idx) ? 1.f : 0.f;
        v.y = (k + 1 == idx) ? 1.f : 0.f;
        v.z = (k + 2 == idx) ? 1.f : 0.f;
        v.w = (k + 3 == idx) ? 1.f : 0.f;
        *(f32x4*)(enc + base + k) = v;
    } else {
        enc[base]        = (idx == 0)    ? 1.f : 0.f;
        enc[base + 1]    = (idx == 1)    ? 1.f : 0.f;
        enc[base + 1022] = (idx == 1022) ? 1.f : 0.f;
        enc[base + 1023] = (idx == 1023) ? 1.f : 0.f;
    }
}

extern "C" void kernel_launch(void* const* d_in, const int* in_sizes, int n_in,
                              void* d_out, int out_size, void* d_ws, size_t ws_size,
                              hipStream_t stream) {
    const float* x   = (const float*)d_in[0];
    const float* emb = (const float*)d_in[1];
    float* out = (float*)d_out;

    char* ws = (char*)d_ws;
    float* lossp = (float*)ws;              // 4096 floats
    int*   hist  = (int*)(ws + 32768);      // 1024 ints
    float* norms = (float*)(ws + 36864);    // 1024 floats
    float* embT  = (float*)(ws + 40960);    // 65536 floats

    float* q      = out + Q_OFF;
    float* o_loss = out + LOSS_OFF;
    float* o_perp = out + PERP_OFF;
    float* enc    = out + ENC_OFF;
    float* idxf   = out + IDX_OFF;

    // scratch in the last 128 one-hot rows (rewritten by vq_tail at the end)
    _Float16* ehs   = (_Float16*)(enc + EHS_F);
    _Float16* els   = (_Float16*)(enc + ELS_F);
    int* fixlist    = (int*)(enc + FIXLIST_I);
    float* fixdelta = (float*)(enc + FIXDELTA_F);
    int* fixcount   = (int*)(enc + FIXCOUNT_I);

    (void)hipMemsetAsync(ws + 32768, 0, 4096, stream);     // hist
    (void)hipMemsetAsync((void*)fixcount, 0, 4, stream);   // fix-up counter

    vq_prep<<<260, 256, 0, stream>>>(emb, embT, ehs, els, norms);
    vq_argmin_fused<<<1024, 256, 0, stream>>>(x, ehs, els, norms, embT, idxf, q,
                                              enc, hist, lossp, fixlist, fixcount);
    vq_fixup<<<FIXCAP, 64, 0, stream>>>(x, embT, norms, fixlist, fixcount,
                                        idxf, q, enc, hist, fixdelta);
    vq_final<<<1, 256, 0, stream>>>(lossp, hist, fixdelta, fixcount, o_loss, o_perp);
    vq_tail<<<128, 256, 0, stream>>>(idxf, enc);
}